// Round 7
// baseline (657.439 us; speedup 1.0000x reference)
//
#include <hip/hip_runtime.h>
#include <hip/hip_bf16.h>

typedef unsigned short ushort_t;
typedef __attribute__((ext_vector_type(8))) short short8;
typedef __attribute__((ext_vector_type(8))) unsigned short ushort8;
typedef __attribute__((ext_vector_type(4))) float f32x4;
typedef __attribute__((ext_vector_type(4))) unsigned int u32x4;
typedef long long i64;

__device__ __forceinline__ ushort_t f2bf(float f) {
  union { float f; unsigned int u; } c; c.f = f;
  unsigned int u = c.u;
  return (ushort_t)((u + 0x7fffu + ((u >> 16) & 1u)) >> 16);
}
__device__ __forceinline__ float bfbits_lo(unsigned int u) {
  union { unsigned int u; float f; } c; c.u = u << 16; return c.f;
}
__device__ __forceinline__ float bfbits_hi(unsigned int u) {
  union { unsigned int u; float f; } c; c.u = u & 0xffff0000u; return c.f;
}

__device__ __forceinline__ void gload_lds16(const void* g, void* l) {
  __builtin_amdgcn_global_load_lds(
      (__attribute__((address_space(1))) void*)(void*)g,
      (__attribute__((address_space(3))) void*)l, 16, 0, 0);
}

__device__ __forceinline__ void bar_lds() {
  asm volatile("s_waitcnt lgkmcnt(0)" ::: "memory");
  __builtin_amdgcn_s_barrier();
  asm volatile("" ::: "memory");
}
__device__ __forceinline__ void bar_full() {
  asm volatile("s_waitcnt vmcnt(0) lgkmcnt(0)" ::: "memory");
  __builtin_amdgcn_s_barrier();
  asm volatile("" ::: "memory");
}

// ---------------- LayerNorm: f32 in -> bf16 out, D=512, one row per wave ----
__global__ __launch_bounds__(256) void ln_kernel(
    const float* __restrict__ x, const float* __restrict__ g,
    const float* __restrict__ be, ushort_t* __restrict__ out)
{
  const int lane = threadIdx.x & 63, wid = threadIdx.x >> 6;
  const size_t row = (size_t)blockIdx.x * 4 + wid;
  const float* xr = x + row * 512 + lane * 8;
  float4 v0 = *(const float4*)xr;
  float4 v1 = *(const float4*)(xr + 4);
  float vv[8] = {v0.x,v0.y,v0.z,v0.w,v1.x,v1.y,v1.z,v1.w};
  float s = 0;
#pragma unroll
  for (int e = 0; e < 8; ++e) s += vv[e];
#pragma unroll
  for (int o = 1; o < 64; o <<= 1) s += __shfl_xor(s, o);
  float mu = s * (1.0f/512.0f);
  float sq = 0;
#pragma unroll
  for (int e = 0; e < 8; ++e) { float d = vv[e]-mu; sq += d*d; }
#pragma unroll
  for (int o = 1; o < 64; o <<= 1) sq += __shfl_xor(sq, o);
  float rinv = rsqrtf(sq * (1.0f/512.0f) + 1e-5f);
  const float* gp = g + lane*8; const float* bp = be + lane*8;
  float4 ga = *(const float4*)gp, gb = *(const float4*)(gp+4);
  float4 ba = *(const float4*)bp, bb4 = *(const float4*)(bp+4);
  float gg[8] = {ga.x,ga.y,ga.z,ga.w,gb.x,gb.y,gb.z,gb.w};
  float bb[8] = {ba.x,ba.y,ba.z,ba.w,bb4.x,bb4.y,bb4.z,bb4.w};
  ushort8 o8;
#pragma unroll
  for (int e = 0; e < 8; ++e) o8[e] = f2bf((vv[e]-mu)*rinv*gg[e] + bb[e]);
  *(ushort8*)(out + row*512 + lane*8) = o8;
}

// ---------------- Weight transpose + bf16 convert: in (K,N) -> out (N,K) ----
__global__ __launch_bounds__(256) void wt_kernel(
    const float* __restrict__ w, ushort_t* __restrict__ wT, int K, int N)
{
  int id = blockIdx.x * 256 + threadIdx.x;
  if (id >= K * N) return;
  int n = id / K, kk = id - n * K;
  wT[id] = f2bf(w[(size_t)kk * N + n]);
}

// ---------------- Rel-table prep ------------------------------------------
// rqp : plain (r,d) bf16, PRE-SCALED by 0.125 (240 rows, zero-padded)
// rkp : plain (r,d) bf16 (240 rows, zero-padded)
// rv8 : plain (d,r) fp8 e4m3, 64 x 256, zero-padded r>=225
// c0  : 240 f32, 0.125 * rel_q[r].rel_k[r]
__global__ __launch_bounds__(256) void prep_rel_kernel(
    const float* __restrict__ rq, const float* __restrict__ rk,
    const float* __restrict__ rv,
    ushort_t* __restrict__ rqp, ushort_t* __restrict__ rkp,
    unsigned char* __restrict__ rv8, float* __restrict__ c0_s)
{
  int id = blockIdx.x * 256 + threadIdx.x;
  if (id < 240*64) {
    int r = id >> 6;
    rqp[id] = (r < 225) ? f2bf(rq[id] * 0.125f) : (ushort_t)0;
    rkp[id] = (r < 225) ? f2bf(rk[id]) : (ushort_t)0;
  }
  if (id < 64*256) {
    int d = id >> 8, r = id & 255;
    float vv = (r < 225) ? rv[r*64+d] : 0.0f;
    int pk = __builtin_amdgcn_cvt_pk_fp8_f32(vv, vv, 0, 0);
    rv8[id] = (unsigned char)(pk & 0xff);
  }
  if (id < 240) {
    float s = 0;
    if (id < 225)
      for (int d2 = 0; d2 < 64; ++d2) s += rq[id*64+d2]*rk[id*64+d2];
    c0_s[id] = s * 0.125f;
  }
}

// ---------------- bf16 GEMM: C = A(MxK) * Bt(NxK)^T, 128x128 tile, BK=64 ----
template<int EPI>
__global__ __launch_bounds__(256) void gemm_kernel(
    const ushort_t* __restrict__ A, const ushort_t* __restrict__ Bt,
    int M, int N, int K,
    const float* __restrict__ bias, const float* __restrict__ resid,
    float* __restrict__ outf, ushort_t* __restrict__ outb,
    ushort_t* __restrict__ qb, ushort_t* __restrict__ kb,
    ushort_t* __restrict__ vtb)
{
  __shared__ ushort_t lds[32768];   // 2 buf x (A 16KB + B 16KB)
  const int tid = threadIdx.x, lane = tid & 63, wid = tid >> 6;
  const int m0 = blockIdx.x * 128, n0 = blockIdx.y * 128;
  const int l15 = lane & 15, lh = lane >> 4;
  const int wm = wid >> 1, wn = wid & 1;

  f32x4 acc[4][4] = {};
  const int NT = K >> 6;

  auto stage = [&](int buf, int kt) {
    const int k0 = kt << 6;
#pragma unroll
    for (int p = 0; p < 4; ++p) {
      const int lofs = p*4096 + wid*1024;               // byte offset in half
      const int row = (lofs + lane*16) >> 7;            // 0..127
      const int sc = ((lane & 7) ^ (row & 7)) << 3;     // swizzled src col
      gload_lds16(A  + (size_t)(m0 + row) * K + (k0 + sc),
                  &lds[buf*16384 + (lofs >> 1)]);
      gload_lds16(Bt + (size_t)(n0 + row) * K + (k0 + sc),
                  &lds[buf*16384 + 8192 + (lofs >> 1)]);
    }
  };

  stage(0, 0);
  __syncthreads();
  for (int t = 0; t < NT; ++t) {
    if (t + 1 < NT) stage((t+1) & 1, t+1);
    const ushort_t* Ab = &lds[(t&1)*16384];
    const ushort_t* Bb = Ab + 8192;
#pragma unroll
    for (int kh = 0; kh < 2; ++kh) {
      const int slotk = kh*4 + lh;
      short8 af[4], bf[4];
#pragma unroll
      for (int mi = 0; mi < 4; ++mi) {
        int row = wm*64 + mi*16 + l15;
        af[mi] = *(const short8*)((const char*)Ab + row*128 + ((slotk ^ (row&7))<<4));
      }
#pragma unroll
      for (int ni = 0; ni < 4; ++ni) {
        int row = wn*64 + ni*16 + l15;
        bf[ni] = *(const short8*)((const char*)Bb + row*128 + ((slotk ^ (row&7))<<4));
      }
#pragma unroll
      for (int mi = 0; mi < 4; ++mi)
#pragma unroll
        for (int ni = 0; ni < 4; ++ni)
          acc[mi][ni] = __builtin_amdgcn_mfma_f32_16x16x32_bf16(
              af[mi], bf[ni], acc[mi][ni], 0, 0, 0);
    }
    __syncthreads();
  }

#pragma unroll
  for (int mi = 0; mi < 4; ++mi)
#pragma unroll
    for (int ni = 0; ni < 4; ++ni)
#pragma unroll
      for (int r = 0; r < 4; ++r) {
        const int grow = m0 + wm*64 + mi*16 + lh*4 + r;
        const int gcol = n0 + wn*64 + ni*16 + l15;
        const float v = acc[mi][ni][r];
        if constexpr (EPI == 0) {
          const int sel = gcol >> 9, c5 = gcol & 511;
          const int hh = c5 >> 6, d = c5 & 63;
          const size_t bh = (size_t)((grow >> 6) * 8 + hh);
          const int i = grow & 63;
          if (sel == 0)      qb[(bh<<12) + i*64 + d] = f2bf(v * 0.125f);
          else if (sel == 1) kb[(bh<<12) + i*64 + d] = f2bf(v);
          else               vtb[(bh<<12) + d*64 + i] = f2bf(v);
        } else if constexpr (EPI == 2) {
          float t2 = v + bias[gcol];
          outb[(size_t)grow * N + gcol] = f2bf(t2 > 0.0f ? t2 : 0.0f);
        } else {
          const size_t o = (size_t)grow * N + gcol;
          outf[o] = v + bias[gcol] + resid[o];
        }
      }
}

// ---------------- Fused relative attention --------------------------------
// One head per 512-thread block (8 waves; wave = (ib, half)).
// Pure-store formulation: logits1 (f32, swizzled [64][64]) from QK^T;
// t23 (u32 = lo bf16 t2+C0, hi bf16 t3) written exactly once per (i,j)
// by the acc2/acc3 scatters. Softmax = vector reads only. No RMW.
// LDS 33728B: logits 16384 | t23 16384 | c0 960; attnS(8K)+S8(16K) alias.
__global__ __launch_bounds__(512, 4) void attn_kernel(
    const ushort_t* __restrict__ qb, const ushort_t* __restrict__ kb,
    const ushort_t* __restrict__ vtb,
    const ushort_t* __restrict__ rkp, const ushort_t* __restrict__ rqp,
    const unsigned char* __restrict__ rv8, const float* __restrict__ c0_g,
    ushort_t* __restrict__ attn_out)
{
  __shared__ char smem[33728];
  char* t23B = smem + 16384;
  float* c0S = (float*)(smem + 32768);
  char* attnSB = smem;          // alias (post-softmax)
  char* S8B = smem + 8192;      // alias (post-softmax)

  const int tid = threadIdx.x, lane = tid & 63, wid = tid >> 6;
  const int ib = wid >> 1, half = wid & 1;
  const int l15 = lane & 15, lh = lane >> 4;
  const int rowA = ib*16 + l15;
  const int bh = blockIdx.x;
  const ushort_t* q  = qb  + ((size_t)bh << 12);
  const ushort_t* k  = kb  + ((size_t)bh << 12);
  const ushort_t* vT = vtb + ((size_t)bh << 12);

  if (tid < 60)
    gload_lds16((const char*)c0_g + tid*16, (char*)c0S + tid*16);
  bar_full();

  // ---- P1a: QK^T (wave pair splits jb) ----------------------------------
  short8 qf0 = *(const short8*)(q + rowA*64 + lh*8);
  short8 qf1 = *(const short8*)(q + rowA*64 + 32 + lh*8);
#pragma unroll
  for (int t = 0; t < 2; ++t) {
    const int jb = half*2 + t;
    short8 b0 = *(const short8*)(k + (jb*16+l15)*64 + lh*8);
    short8 b1 = *(const short8*)(k + (jb*16+l15)*64 + 32 + lh*8);
    f32x4 a = {};
    a = __builtin_amdgcn_mfma_f32_16x16x32_bf16(qf0, b0, a, 0,0,0);
    a = __builtin_amdgcn_mfma_f32_16x16x32_bf16(qf1, b1, a, 0,0,0);
#pragma unroll
    for (int r = 0; r < 4; ++r) {
      const int i = ib*16 + lh*4 + r;
      const int gcol = jb*16 + l15;
      *(float*)(smem + i*256 + ((((gcol>>2) ^ (i&7)))<<4) + (gcol&3)*4) = a[r];
    }
  }

  // ---- P1b: t2 = q @ rel_k^T + C0, pure store into t23.lo ---------------
  {
    const int nc0 = half ? 8 : 0, nc1 = half ? 15 : 8;
    for (int nc = nc0; nc < nc1; ++nc) {
      const ushort_t* rp = rkp + (nc*16 + l15)*64;
      short8 b0 = *(const short8*)(rp + lh*8);
      short8 b1 = *(const short8*)(rp + 32 + lh*8);
      f32x4 a = {};
      a = __builtin_amdgcn_mfma_f32_16x16x32_bf16(qf0, b0, a, 0,0,0);
      a = __builtin_amdgcn_mfma_f32_16x16x32_bf16(qf1, b1, a, 0,0,0);
      const int rr = nc*16 + l15;
      const float c0v = c0S[rr];
      const int dx = rr / 15, dy = rr - dx*15;
#pragma unroll
      for (int r = 0; r < 4; ++r) {
        const int i = ib*16 + lh*4 + r;
        const int xj = (i >> 3) - dx + 7, yj = (i & 7) - dy + 7;
        if ((unsigned)xj < 8u && (unsigned)yj < 8u) {
          const int j = xj*8 + yj;
          *(ushort_t*)(t23B + i*256 + (((j>>2) ^ (i&7))<<4) + (j&3)*4)
              = f2bf(a[r] + c0v);
        }
      }
    }
  }

  // ---- P1c: t3 = k @ rel_q^T (pre-scaled), pure store into t23.hi -------
  {
    short8 kf0 = *(const short8*)(k + rowA*64 + lh*8);
    short8 kf1 = *(const short8*)(k + rowA*64 + 32 + lh*8);
    const int nc0 = half ? 8 : 0, nc1 = half ? 15 : 8;
    for (int nc = nc0; nc < nc1; ++nc) {
      const ushort_t* rp = rqp + (nc*16 + l15)*64;
      short8 b0 = *(const short8*)(rp + lh*8);
      short8 b1 = *(const short8*)(rp + 32 + lh*8);
      f32x4 a = {};
      a = __builtin_amdgcn_mfma_f32_16x16x32_bf16(kf0, b0, a, 0,0,0);
      a = __builtin_amdgcn_mfma_f32_16x16x32_bf16(kf1, b1, a, 0,0,0);
      const int rr = nc*16 + l15;
      const int dx = rr / 15, dy = rr - dx*15;
#pragma unroll
      for (int r = 0; r < 4; ++r) {
        const int j = ib*16 + lh*4 + r;     // this wave's rows act as column j
        const int xi = (j >> 3) + dx - 7, yi = (j & 7) + dy - 7;
        if ((unsigned)xi < 8u && (unsigned)yi < 8u) {
          const int i = xi*8 + yi;
          *(ushort_t*)(t23B + i*256 + (((j>>2) ^ (i&7))<<4) + (j&3)*4 + 2)
              = f2bf(a[r]);
        }
      }
    }
  }
  bar_lds();  // BAR1: logits + t23 complete

  // ---- P2: softmax (pure vector reads) -----------------------------------
  const int i = tid >> 3, qq = tid & 7;
  float av[8];
  {
    float mx = -1e30f;
#pragma unroll
    for (int h = 0; h < 2; ++h) {
      const int g = 2*qq + h;
      const int off = i*256 + ((g ^ (i&7))<<4);
      f32x4 lf = *(const f32x4*)(smem + off);
      u32x4 u  = *(const u32x4*)(t23B + off);
#pragma unroll
      for (int e = 0; e < 4; ++e) {
        float v = lf[e] + bfbits_lo(u[e]) + bfbits_hi(u[e]);
        av[h*4+e] = v; mx = fmaxf(mx, v);
      }
    }
    mx = fmaxf(mx, __shfl_xor(mx, 1));
    mx = fmaxf(mx, __shfl_xor(mx, 2));
    mx = fmaxf(mx, __shfl_xor(mx, 4));
    float s = 0;
#pragma unroll
    for (int e = 0; e < 8; ++e) { float ev = __expf(av[e]-mx); av[e] = ev; s += ev; }
    s += __shfl_xor(s, 1); s += __shfl_xor(s, 2); s += __shfl_xor(s, 4);
    const float inv = 1.0f / s;
#pragma unroll
    for (int e = 0; e < 8; ++e) av[e] *= inv;
  }
  bar_lds();  // BAR2: all logits/t23 reads done; overlay may be rewritten

  // ---- P3: write attnS (bf16) + S8 (fp8 scatter) -------------------------
  {
    ushort8 w;
#pragma unroll
    for (int e = 0; e < 8; ++e) w[e] = f2bf(av[e]);
    *(ushort8*)(attnSB + i*128 + ((qq ^ (i&7))<<4)) = w;
#pragma unroll
    for (int u8 = 0; u8 < 4; ++u8)
      *(i64*)(S8B + i*256 + (((qq*4 + u8) ^ (i&7))<<3)) = 0;
    const int xi8 = i >> 3, yi8 = i & 7;
#pragma unroll
    for (int jj = 0; jj < 8; jj += 2) {
      const int j0 = qq*8 + jj;
      int pk = __builtin_amdgcn_cvt_pk_fp8_f32(av[jj], av[jj+1], 0, 0);
      const int rr0 = (xi8 - (j0>>3) + 7)*15 + (yi8 - (j0&7) + 7);
      const int rr1 = (xi8 - ((j0+1)>>3) + 7)*15 + (yi8 - ((j0+1)&7) + 7);
      *(unsigned char*)(S8B + i*256 + (((rr0>>3) ^ (i&7))<<3) + (rr0&7))
          = (unsigned char)(pk & 0xff);
      *(unsigned char*)(S8B + i*256 + (((rr1>>3) ^ (i&7))<<3) + (rr1&7))
          = (unsigned char)((pk >> 8) & 0xff);
    }
  }
  bar_lds();  // BAR3: attnS/S8 complete

  // ---- P4: out = attn @ v (bf16) + S @ rel_v^T (fp8), 2 tiles per wave ---
#pragma unroll
  for (int t = 0; t < 2; ++t) {
    const int db = half*2 + t;
    f32x4 a = {};
#pragma unroll
    for (int ks = 0; ks < 8; ++ks) {
      i64 a8 = *(const i64*)(S8B + rowA*256 + (((ks*4+lh) ^ (rowA&7))<<3));
      i64 b8 = *(const i64*)(rv8 + (size_t)(db*16+l15)*256 + ks*32 + lh*8);
      a = __builtin_amdgcn_mfma_f32_16x16x32_fp8_fp8(a8, b8, a, 0,0,0);
    }
    {
      short8 bv0 = *(const short8*)(vT + (db*16+l15)*64 + lh*8);
      short8 bv1 = *(const short8*)(vT + (db*16+l15)*64 + 32 + lh*8);
      short8 aa0 = *(const short8*)(attnSB + rowA*128 + ((lh ^ (rowA&7))<<4));
      short8 aa1 = *(const short8*)(attnSB + rowA*128 + (((4+lh) ^ (rowA&7))<<4));
      a = __builtin_amdgcn_mfma_f32_16x16x32_bf16(aa0, bv0, a, 0,0,0);
      a = __builtin_amdgcn_mfma_f32_16x16x32_bf16(aa1, bv1, a, 0,0,0);
    }
    const int b_idx = bh >> 3, hh = bh & 7;
#pragma unroll
    for (int r = 0; r < 4; ++r)
      attn_out[((size_t)(b_idx*64 + ib*16 + lh*4 + r))*512 + hh*64 + db*16 + l15]
          = f2bf(a[r]);
  }
}

// ---------------------------------------------------------------------------
extern "C" void kernel_launch(void* const* d_in, const int* in_sizes, int n_in,
                              void* d_out, int out_size, void* d_ws, size_t ws_size,
                              hipStream_t stream)
{
  (void)in_sizes; (void)n_in; (void)out_size; (void)ws_size;
  const float* x     = (const float*)d_in[0];
  const float* w_qkv = (const float*)d_in[1];
  const float* w_proj= (const float*)d_in[2];
  const float* b_proj= (const float*)d_in[3];
  const float* w1    = (const float*)d_in[4];
  const float* b1    = (const float*)d_in[5];
  const float* w2    = (const float*)d_in[6];
  const float* b2    = (const float*)d_in[7];
  const float* g1    = (const float*)d_in[8];
  const float* be1   = (const float*)d_in[9];
  const float* g2    = (const float*)d_in[10];
  const float* be2   = (const float*)d_in[11];
  const float* rel_q = (const float*)d_in[12];
  const float* rel_k = (const float*)d_in[13];
  const float* rel_v = (const float*)d_in[14];

  char* ws = (char*)d_ws;
  const size_t MB = 1ull << 20;
  ushort_t* h      = (ushort_t*)(ws);            // 32MiB (reused as h2)
  ushort_t* qb     = (ushort_t*)(ws + 32*MB);
  ushort_t* kb     = (ushort_t*)(ws + 64*MB);
  ushort_t* vtb    = (ushort_t*)(ws + 96*MB);
  ushort_t* attn_o = (ushort_t*)(ws + 128*MB);
  ushort_t* ff     = (ushort_t*)(ws + 32*MB);    // aliases qb..attn_o (dead)
  float*    x_mid  = (float*)(ws + 160*MB);      // 64MiB
  char* wreg = ws + 224*MB;
  ushort_t* wqkvT = (ushort_t*)(wreg);
  ushort_t* wprojT= (ushort_t*)(wreg + 1572864);
  ushort_t* w1T   = (ushort_t*)(wreg + 2097152);
  ushort_t* w2T   = (ushort_t*)(wreg + 4194304);
  ushort_t*      rkp  = (ushort_t*)(wreg + 6291456);
  ushort_t*      rqp  = (ushort_t*)(wreg + 6322176);
  unsigned char* rv8  = (unsigned char*)(wreg + 6352896);
  float*         c0_s = (float*)(wreg + 6369280);

  wt_kernel<<<(512*1536+255)/256, 256, 0, stream>>>(w_qkv, wqkvT, 512, 1536);
  wt_kernel<<<(512*512+255)/256, 256, 0, stream>>>(w_proj, wprojT, 512, 512);
  wt_kernel<<<(512*2048+255)/256, 256, 0, stream>>>(w1, w1T, 512, 2048);
  wt_kernel<<<(2048*512+255)/256, 256, 0, stream>>>(w2, w2T, 2048, 512);
  prep_rel_kernel<<<64, 256, 0, stream>>>(rel_q, rel_k, rel_v,
      rqp, rkp, rv8, c0_s);

  ln_kernel<<<8192, 256, 0, stream>>>(x, g1, be1, h);
  gemm_kernel<0><<<dim3(256,12), 256, 0, stream>>>(h, wqkvT, 32768, 1536, 512,
      nullptr, nullptr, nullptr, nullptr, qb, kb, vtb);
  attn_kernel<<<4096, 512, 0, stream>>>(qb, kb, vtb,
      rkp, rqp, rv8, c0_s, attn_o);
  gemm_kernel<1><<<dim3(256,4), 256, 0, stream>>>(attn_o, wprojT, 32768, 512, 512,
      b_proj, x, x_mid, nullptr, nullptr, nullptr, nullptr);
  ln_kernel<<<8192, 256, 0, stream>>>(x_mid, g2, be2, h);
  gemm_kernel<2><<<dim3(256,16), 256, 0, stream>>>(h, w1T, 32768, 2048, 512,
      b1, nullptr, nullptr, ff, nullptr, nullptr, nullptr);
  gemm_kernel<3><<<dim3(256,4), 256, 0, stream>>>(ff, w2T, 32768, 512, 2048,
      b2, x_mid, (float*)d_out, nullptr, nullptr, nullptr, nullptr);
}

// Round 8
// 605.675 us; speedup vs baseline: 1.0855x; 1.0855x over previous
//
#include <hip/hip_runtime.h>
#include <hip/hip_bf16.h>

typedef unsigned short ushort_t;
typedef __attribute__((ext_vector_type(8))) short short8;
typedef __attribute__((ext_vector_type(8))) unsigned short ushort8;
typedef __attribute__((ext_vector_type(4))) float f32x4;
typedef __attribute__((ext_vector_type(4))) unsigned int u32x4;
typedef long long i64;

__device__ __forceinline__ ushort_t f2bf(float f) {
  union { float f; unsigned int u; } c; c.f = f;
  unsigned int u = c.u;
  return (ushort_t)((u + 0x7fffu + ((u >> 16) & 1u)) >> 16);
}
__device__ __forceinline__ float bfbits_lo(unsigned int u) {
  union { unsigned int u; float f; } c; c.u = u << 16; return c.f;
}
__device__ __forceinline__ float bfbits_hi(unsigned int u) {
  union { unsigned int u; float f; } c; c.u = u & 0xffff0000u; return c.f;
}

__device__ __forceinline__ void gload_lds16(const void* g, void* l) {
  __builtin_amdgcn_global_load_lds(
      (__attribute__((address_space(1))) void*)(void*)g,
      (__attribute__((address_space(3))) void*)l, 16, 0, 0);
}

__device__ __forceinline__ void bar_lds() {
  asm volatile("s_waitcnt lgkmcnt(0)" ::: "memory");
  __builtin_amdgcn_s_barrier();
  asm volatile("" ::: "memory");
}
__device__ __forceinline__ void bar_full() {
  asm volatile("s_waitcnt vmcnt(0) lgkmcnt(0)" ::: "memory");
  __builtin_amdgcn_s_barrier();
  asm volatile("" ::: "memory");
}

// ---------------- LayerNorm: f32 in -> bf16 out, D=512, one row per wave ----
__global__ __launch_bounds__(256) void ln_kernel(
    const float* __restrict__ x, const float* __restrict__ g,
    const float* __restrict__ be, ushort_t* __restrict__ out)
{
  const int lane = threadIdx.x & 63, wid = threadIdx.x >> 6;
  const size_t row = (size_t)blockIdx.x * 4 + wid;
  const float* xr = x + row * 512 + lane * 8;
  float4 v0 = *(const float4*)xr;
  float4 v1 = *(const float4*)(xr + 4);
  float vv[8] = {v0.x,v0.y,v0.z,v0.w,v1.x,v1.y,v1.z,v1.w};
  float s = 0;
#pragma unroll
  for (int e = 0; e < 8; ++e) s += vv[e];
#pragma unroll
  for (int o = 1; o < 64; o <<= 1) s += __shfl_xor(s, o);
  float mu = s * (1.0f/512.0f);
  float sq = 0;
#pragma unroll
  for (int e = 0; e < 8; ++e) { float d = vv[e]-mu; sq += d*d; }
#pragma unroll
  for (int o = 1; o < 64; o <<= 1) sq += __shfl_xor(sq, o);
  float rinv = rsqrtf(sq * (1.0f/512.0f) + 1e-5f);
  const float* gp = g + lane*8; const float* bp = be + lane*8;
  float4 ga = *(const float4*)gp, gb = *(const float4*)(gp+4);
  float4 ba = *(const float4*)bp, bb4 = *(const float4*)(bp+4);
  float gg[8] = {ga.x,ga.y,ga.z,ga.w,gb.x,gb.y,gb.z,gb.w};
  float bb[8] = {ba.x,ba.y,ba.z,ba.w,bb4.x,bb4.y,bb4.z,bb4.w};
  ushort8 o8;
#pragma unroll
  for (int e = 0; e < 8; ++e) o8[e] = f2bf((vv[e]-mu)*rinv*gg[e] + bb[e]);
  *(ushort8*)(out + row*512 + lane*8) = o8;
}

// ---------------- Weight transpose (tiled, coalesced both sides) -----------
__global__ __launch_bounds__(256) void wt_kernel(
    const float* __restrict__ w, ushort_t* __restrict__ wT, int K, int N)
{
  __shared__ float t[64][65];
  const int k0 = blockIdx.x * 64, n0 = blockIdx.y * 64;
  const int c = threadIdx.x & 63, r4 = threadIdx.x >> 6;
#pragma unroll
  for (int rr = 0; rr < 64; rr += 4)
    t[rr + r4][c] = w[(size_t)(k0 + rr + r4) * N + n0 + c];
  __syncthreads();
#pragma unroll
  for (int rr = 0; rr < 64; rr += 4)
    wT[(size_t)(n0 + rr + r4) * K + k0 + c] = f2bf(t[c][rr + r4]);
}

// ---------------- Rel-table prep ------------------------------------------
// rqp/rkp: (r,d) bf16, 256 rows (zero-padded >=225); rqp pre-scaled 0.125
// rv8    : (d,r) fp8 e4m3, 64 x 256
// tbl    : u32[256]: lo16 = bf16(0.125*rq[r].rk[r]), b16-23 = dx, b24-31 = dy
__global__ __launch_bounds__(256) void prep_rel_kernel(
    const float* __restrict__ rq, const float* __restrict__ rk,
    const float* __restrict__ rv,
    ushort_t* __restrict__ rqp, ushort_t* __restrict__ rkp,
    unsigned char* __restrict__ rv8, unsigned int* __restrict__ tbl)
{
  int id = blockIdx.x * 256 + threadIdx.x;
  if (id < 256*64) {
    int r = id >> 6;
    rqp[id] = (r < 225) ? f2bf(rq[id] * 0.125f) : (ushort_t)0;
    rkp[id] = (r < 225) ? f2bf(rk[id]) : (ushort_t)0;
  }
  if (id < 64*256) {
    int d = id >> 8, r = id & 255;
    float vv = (r < 225) ? rv[r*64+d] : 0.0f;
    int pk = __builtin_amdgcn_cvt_pk_fp8_f32(vv, vv, 0, 0);
    rv8[id] = (unsigned char)(pk & 0xff);
  }
  if (id < 256) {
    float s = 0; unsigned dx = 255, dy = 255;
    if (id < 225) {
      for (int d2 = 0; d2 < 64; ++d2) s += rq[id*64+d2]*rk[id*64+d2];
      dx = id / 15; dy = id - dx*15;
    }
    tbl[id] = (unsigned)f2bf(s * 0.125f) | (dx << 16) | (dy << 24);
  }
}

// ---------------- bf16 GEMM: 256x256 tile, BK=64, 512 thr, 128KB LDS -------
// C = A(MxK) * Bt(NxK)^T.  Waves 2(M) x 4(N); per-wave 128x64 via acc[8][4].
// EPI 0: scatter qkv   EPI 1/3: +bias +resid -> f32   EPI 2: relu+bias -> bf16
template<int EPI>
__global__ __launch_bounds__(512, 2) void gemm_kernel(
    const ushort_t* __restrict__ A, const ushort_t* __restrict__ Bt,
    int M, int N, int K,
    const float* __restrict__ bias, const float* __restrict__ resid,
    float* __restrict__ outf, ushort_t* __restrict__ outb,
    ushort_t* __restrict__ qb, ushort_t* __restrict__ kb,
    ushort_t* __restrict__ vtb)
{
  __shared__ __align__(16) ushort_t lds[65536];  // 2 x (A 32KB + B 32KB)
  const int tid = threadIdx.x, lane = tid & 63, wid = tid >> 6;
  const int m0 = blockIdx.x * 256, n0 = blockIdx.y * 256;
  const int l15 = lane & 15, lh = lane >> 4;
  const int wm = wid >> 2, wn = wid & 3;

  f32x4 acc[8][4] = {};
  const int NT = K >> 6;

  auto stage = [&](int buf, int kt) {
    const int k0 = kt << 6;
#pragma unroll
    for (int p = 0; p < 4; ++p) {
      const int lofs = p*8192 + tid*16;            // byte offset in 32KB half
      const int row = lofs >> 7;                   // 0..255
      const int sc = ((tid & 7) ^ (row & 7)) << 3; // swizzled src col (elems)
      gload_lds16(A  + (size_t)(m0 + row) * K + (k0 + sc),
                  &lds[buf*32768 + (lofs >> 1)]);
      gload_lds16(Bt + (size_t)(n0 + row) * K + (k0 + sc),
                  &lds[buf*32768 + 16384 + (lofs >> 1)]);
    }
  };

  stage(0, 0);
  __syncthreads();
  for (int t = 0; t < NT; ++t) {
    if (t + 1 < NT) stage((t+1) & 1, t+1);
    const ushort_t* Ab = &lds[(t&1)*32768];
    const ushort_t* Bb = Ab + 16384;
    short8 bfr[4][2];
#pragma unroll
    for (int ni = 0; ni < 4; ++ni) {
      const int row = wn*64 + ni*16 + l15;
#pragma unroll
      for (int kh = 0; kh < 2; ++kh)
        bfr[ni][kh] = *(const short8*)((const char*)Bb + row*128 +
                                       (((kh*4+lh) ^ (row&7))<<4));
    }
#pragma unroll
    for (int mi = 0; mi < 8; ++mi) {
      const int row = wm*128 + mi*16 + l15;
      short8 a0 = *(const short8*)((const char*)Ab + row*128 + ((lh     ^ (row&7))<<4));
      short8 a1 = *(const short8*)((const char*)Ab + row*128 + (((4+lh) ^ (row&7))<<4));
#pragma unroll
      for (int ni = 0; ni < 4; ++ni) {
        acc[mi][ni] = __builtin_amdgcn_mfma_f32_16x16x32_bf16(a0, bfr[ni][0], acc[mi][ni], 0,0,0);
        acc[mi][ni] = __builtin_amdgcn_mfma_f32_16x16x32_bf16(a1, bfr[ni][1], acc[mi][ni], 0,0,0);
      }
    }
    __syncthreads();
  }

#pragma unroll
  for (int mi = 0; mi < 8; ++mi)
#pragma unroll
    for (int ni = 0; ni < 4; ++ni)
#pragma unroll
      for (int r = 0; r < 4; ++r) {
        const int grow = m0 + wm*128 + mi*16 + lh*4 + r;
        const int gcol = n0 + wn*64 + ni*16 + l15;
        const float v = acc[mi][ni][r];
        if constexpr (EPI == 0) {
          const int sel = gcol >> 9, c5 = gcol & 511;
          const int hh = c5 >> 6, d = c5 & 63;
          const size_t bh = (size_t)((grow >> 6) * 8 + hh);
          const int i = grow & 63;
          if (sel == 0)      qb[(bh<<12) + i*64 + d] = f2bf(v * 0.125f);
          else if (sel == 1) kb[(bh<<12) + i*64 + d] = f2bf(v);
          else               vtb[(bh<<12) + d*64 + i] = f2bf(v);
        } else if constexpr (EPI == 2) {
          float t2 = v + bias[gcol];
          outb[(size_t)grow * N + gcol] = f2bf(t2 > 0.0f ? t2 : 0.0f);
        } else {
          const size_t o = (size_t)grow * N + gcol;
          outf[o] = v + bias[gcol] + resid[o];
        }
      }
}

// ---------------- Fused relative attention --------------------------------
// One head per 512-thread block (8 waves; wave = (ib, half)).
// LDS 33792B: qk f32 [64] swz rows (16384) | t23 u32 (16384) | tbl u32[256].
// attnS(8K)+S8(16K) alias onto qk/t23 after BAR2.
__global__ __launch_bounds__(512, 4) void attn_kernel(
    const ushort_t* __restrict__ qb, const ushort_t* __restrict__ kb,
    const ushort_t* __restrict__ vtb,
    const ushort_t* __restrict__ rkp, const ushort_t* __restrict__ rqp,
    const unsigned char* __restrict__ rv8, const unsigned int* __restrict__ tbl_g,
    ushort_t* __restrict__ attn_out)
{
  __shared__ char smem[33792];
  char* t23B = smem + 16384;
  unsigned int* tblS = (unsigned int*)(smem + 32768);
  char* attnSB = smem;          // alias (post-softmax)
  char* S8B = smem + 8192;      // alias (post-softmax)

  const int tid = threadIdx.x, lane = tid & 63, wid = tid >> 6;
  const int ib = wid >> 1, half = wid & 1;
  const int l15 = lane & 15, lh = lane >> 4;
  const int rowA = ib*16 + l15;
  const int bh = blockIdx.x;
  const ushort_t* q  = qb  + ((size_t)bh << 12);
  const ushort_t* k  = kb  + ((size_t)bh << 12);
  const ushort_t* vT = vtb + ((size_t)bh << 12);

  if (tid < 64)
    gload_lds16((const char*)tbl_g + tid*16, (char*)tblS + tid*16);
  bar_full();

  // per-r row constants
  const int ibase = ib*16 + lh*4;
  int xi7[4], yi7[4];
#pragma unroll
  for (int r = 0; r < 4; ++r) {
    const int i = ibase + r;
    xi7[r] = (i >> 3) + 7; yi7[r] = (i & 7) + 7;
  }

  // ---- P1a: QK^T (wave pair splits jb) ----------------------------------
  short8 qf0 = *(const short8*)(q + rowA*64 + lh*8);
  short8 qf1 = *(const short8*)(q + rowA*64 + 32 + lh*8);
#pragma unroll
  for (int t = 0; t < 2; ++t) {
    const int jb = half*2 + t;
    short8 b0 = *(const short8*)(k + (jb*16+l15)*64 + lh*8);
    short8 b1 = *(const short8*)(k + (jb*16+l15)*64 + 32 + lh*8);
    f32x4 a = {};
    a = __builtin_amdgcn_mfma_f32_16x16x32_bf16(qf0, b0, a, 0,0,0);
    a = __builtin_amdgcn_mfma_f32_16x16x32_bf16(qf1, b1, a, 0,0,0);
#pragma unroll
    for (int r = 0; r < 4; ++r) {
      const int i = ibase + r;
      const int gcol = jb*16 + l15;
      *(float*)(smem + i*256 + ((((gcol>>2) ^ (i&7)))<<4) + (gcol&3)*4) = a[r];
    }
  }

  // ---- P1b: t2 = q @ rel_k^T + C0, pure store into t23.lo ---------------
#pragma unroll
  for (int s = 0; s < 8; ++s) {
    const int nc = half*8 + s;
    const int rowr = nc*16 + l15;
    const ushort_t* rp = rkp + rowr*64;
    short8 b0 = *(const short8*)(rp + lh*8);
    short8 b1 = *(const short8*)(rp + 32 + lh*8);
    f32x4 a = {};
    a = __builtin_amdgcn_mfma_f32_16x16x32_bf16(qf0, b0, a, 0,0,0);
    a = __builtin_amdgcn_mfma_f32_16x16x32_bf16(qf1, b1, a, 0,0,0);
    const unsigned tb = tblS[rowr];
    const float c0v = bfbits_lo(tb);
    const int dx = (tb >> 16) & 0xff, dy = tb >> 24;
#pragma unroll
    for (int r = 0; r < 4; ++r) {
      const int xj = xi7[r] - dx, yj = yi7[r] - dy;
      if (((xj | yj) & ~7) == 0) {
        const int i = ibase + r;
        const int j = xj*8 + yj;
        *(ushort_t*)(t23B + i*256 + (((j>>2) ^ (i&7))<<4) + (j&3)*4)
            = f2bf(a[r] + c0v);
      }
    }
  }

  // ---- P1c: t3 = k @ rel_q^T (pre-scaled), pure store into t23.hi -------
  {
    short8 kf0 = *(const short8*)(k + rowA*64 + lh*8);
    short8 kf1 = *(const short8*)(k + rowA*64 + 32 + lh*8);
#pragma unroll
    for (int s = 0; s < 8; ++s) {
      const int nc = half*8 + s;
      const int rowr = nc*16 + l15;
      const ushort_t* rp = rqp + rowr*64;
      short8 b0 = *(const short8*)(rp + lh*8);
      short8 b1 = *(const short8*)(rp + 32 + lh*8);
      f32x4 a = {};
      a = __builtin_amdgcn_mfma_f32_16x16x32_bf16(kf0, b0, a, 0,0,0);
      a = __builtin_amdgcn_mfma_f32_16x16x32_bf16(kf1, b1, a, 0,0,0);
      const unsigned tb = tblS[rowr];
      const int dx = (tb >> 16) & 0xff, dy = tb >> 24;
#pragma unroll
      for (int r = 0; r < 4; ++r) {
        const int xi = xi7[r] + dx - 14, yi = yi7[r] + dy - 14;
        if (((xi | yi) & ~7) == 0) {
          const int i2 = xi*8 + yi;
          const int j = ibase + r;
          *(ushort_t*)(t23B + i2*256 + (((j>>2) ^ (i2&7))<<4) + (j&3)*4 + 2)
              = f2bf(a[r]);
        }
      }
    }
  }
  bar_lds();  // BAR1: logits + t23 complete

  // ---- P2: softmax (pure vector reads) -----------------------------------
  const int i = tid >> 3, qq = tid & 7;
  float av[8];
  {
    float mx = -1e30f;
#pragma unroll
    for (int h = 0; h < 2; ++h) {
      const int g = 2*qq + h;
      const int off = i*256 + ((g ^ (i&7))<<4);
      f32x4 lf = *(const f32x4*)(smem + off);
      u32x4 u  = *(const u32x4*)(t23B + off);
#pragma unroll
      for (int e = 0; e < 4; ++e) {
        float v = lf[e] + bfbits_lo(u[e]) + bfbits_hi(u[e]);
        av[h*4+e] = v; mx = fmaxf(mx, v);
      }
    }
    mx = fmaxf(mx, __shfl_xor(mx, 1));
    mx = fmaxf(mx, __shfl_xor(mx, 2));
    mx = fmaxf(mx, __shfl_xor(mx, 4));
    float s = 0;
#pragma unroll
    for (int e = 0; e < 8; ++e) { float ev = __expf(av[e]-mx); av[e] = ev; s += ev; }
    s += __shfl_xor(s, 1); s += __shfl_xor(s, 2); s += __shfl_xor(s, 4);
    const float inv = 1.0f / s;
#pragma unroll
    for (int e = 0; e < 8; ++e) av[e] *= inv;
  }
  bar_lds();  // BAR2: all logits/t23 reads done; overlay may be rewritten

  // ---- P3: write attnS (bf16) + S8 (fp8 scatter) -------------------------
  {
    ushort8 w;
#pragma unroll
    for (int e = 0; e < 8; ++e) w[e] = f2bf(av[e]);
    *(ushort8*)(attnSB + i*128 + ((qq ^ (i&7))<<4)) = w;
#pragma unroll
    for (int u8 = 0; u8 < 4; ++u8)
      *(i64*)(S8B + i*256 + (((qq*4 + u8) ^ (i&7))<<3)) = 0;
    const int xi8 = i >> 3, yi8 = i & 7;
#pragma unroll
    for (int jj = 0; jj < 8; jj += 2) {
      const int j0 = qq*8 + jj;
      int pk = __builtin_amdgcn_cvt_pk_fp8_f32(av[jj], av[jj+1], 0, 0);
      const int rr0 = (xi8 - (j0>>3) + 7)*15 + (yi8 - (j0&7) + 7);
      const int rr1 = (xi8 - ((j0+1)>>3) + 7)*15 + (yi8 - ((j0+1)&7) + 7);
      *(unsigned char*)(S8B + i*256 + (((rr0>>3) ^ (i&7))<<3) + (rr0&7))
          = (unsigned char)(pk & 0xff);
      *(unsigned char*)(S8B + i*256 + (((rr1>>3) ^ (i&7))<<3) + (rr1&7))
          = (unsigned char)((pk >> 8) & 0xff);
    }
  }
  bar_lds();  // BAR3: attnS/S8 complete

  // ---- P4: out = attn @ v (bf16) + S @ rel_v^T (fp8), 2 tiles per wave ---
#pragma unroll
  for (int t = 0; t < 2; ++t) {
    const int db = half*2 + t;
    f32x4 a = {};
#pragma unroll
    for (int ks = 0; ks < 8; ++ks) {
      i64 a8 = *(const i64*)(S8B + rowA*256 + (((ks*4+lh) ^ (rowA&7))<<3));
      i64 b8 = *(const i64*)(rv8 + (size_t)(db*16+l15)*256 + ks*32 + lh*8);
      a = __builtin_amdgcn_mfma_f32_16x16x32_fp8_fp8(a8, b8, a, 0,0,0);
    }
    {
      short8 bv0 = *(const short8*)(vT + (db*16+l15)*64 + lh*8);
      short8 bv1 = *(const short8*)(vT + (db*16+l15)*64 + 32 + lh*8);
      short8 aa0 = *(const short8*)(attnSB + rowA*128 + ((lh ^ (rowA&7))<<4));
      short8 aa1 = *(const short8*)(attnSB + rowA*128 + (((4+lh) ^ (rowA&7))<<4));
      a = __builtin_amdgcn_mfma_f32_16x16x32_bf16(aa0, bv0, a, 0,0,0);
      a = __builtin_amdgcn_mfma_f32_16x16x32_bf16(aa1, bv1, a, 0,0,0);
    }
    const int b_idx = bh >> 3, hh = bh & 7;
#pragma unroll
    for (int r = 0; r < 4; ++r)
      attn_out[((size_t)(b_idx*64 + ib*16 + lh*4 + r))*512 + hh*64 + db*16 + l15]
          = f2bf(a[r]);
  }
}

// ---------------------------------------------------------------------------
extern "C" void kernel_launch(void* const* d_in, const int* in_sizes, int n_in,
                              void* d_out, int out_size, void* d_ws, size_t ws_size,
                              hipStream_t stream)
{
  (void)in_sizes; (void)n_in; (void)out_size; (void)ws_size;
  const float* x     = (const float*)d_in[0];
  const float* w_qkv = (const float*)d_in[1];
  const float* w_proj= (const float*)d_in[2];
  const float* b_proj= (const float*)d_in[3];
  const float* w1    = (const float*)d_in[4];
  const float* b1    = (const float*)d_in[5];
  const float* w2    = (const float*)d_in[6];
  const float* b2    = (const float*)d_in[7];
  const float* g1    = (const float*)d_in[8];
  const float* be1   = (const float*)d_in[9];
  const float* g2    = (const float*)d_in[10];
  const float* be2   = (const float*)d_in[11];
  const float* rel_q = (const float*)d_in[12];
  const float* rel_k = (const float*)d_in[13];
  const float* rel_v = (const float*)d_in[14];

  char* ws = (char*)d_ws;
  const size_t MB = 1ull << 20;
  ushort_t* h      = (ushort_t*)(ws);            // 32MiB (reused as h2)
  ushort_t* qb     = (ushort_t*)(ws + 32*MB);
  ushort_t* kb     = (ushort_t*)(ws + 64*MB);
  ushort_t* vtb    = (ushort_t*)(ws + 96*MB);
  ushort_t* attn_o = (ushort_t*)(ws + 128*MB);
  ushort_t* ff     = (ushort_t*)(ws + 32*MB);    // aliases qb..attn_o (dead)
  float*    x_mid  = (float*)(ws + 160*MB);      // 64MiB
  char* wreg = ws + 224*MB;
  ushort_t* wqkvT = (ushort_t*)(wreg);
  ushort_t* wprojT= (ushort_t*)(wreg + 1572864);
  ushort_t* w1T   = (ushort_t*)(wreg + 2097152);
  ushort_t* w2T   = (ushort_t*)(wreg + 4194304);
  ushort_t*      rkp  = (ushort_t*)(wreg + 6291456);   // 256x64 bf16
  ushort_t*      rqp  = (ushort_t*)(wreg + 6324224);   // 256x64 bf16
  unsigned char* rv8  = (unsigned char*)(wreg + 6356992); // 64x256 fp8
  unsigned int*  tbl  = (unsigned int*)(wreg + 6373376);  // u32[256]

  wt_kernel<<<dim3(8,24), 256, 0, stream>>>(w_qkv, wqkvT, 512, 1536);
  wt_kernel<<<dim3(8,8),  256, 0, stream>>>(w_proj, wprojT, 512, 512);
  wt_kernel<<<dim3(8,32), 256, 0, stream>>>(w1, w1T, 512, 2048);
  wt_kernel<<<dim3(32,8), 256, 0, stream>>>(w2, w2T, 2048, 512);
  prep_rel_kernel<<<64, 256, 0, stream>>>(rel_q, rel_k, rel_v,
      rqp, rkp, rv8, tbl);

  ln_kernel<<<8192, 256, 0, stream>>>(x, g1, be1, h);
  gemm_kernel<0><<<dim3(128,6), 512, 0, stream>>>(h, wqkvT, 32768, 1536, 512,
      nullptr, nullptr, nullptr, nullptr, qb, kb, vtb);
  attn_kernel<<<4096, 512, 0, stream>>>(qb, kb, vtb,
      rkp, rqp, rv8, tbl, attn_o);
  gemm_kernel<1><<<dim3(128,2), 512, 0, stream>>>(attn_o, wprojT, 32768, 512, 512,
      b_proj, x, x_mid, nullptr, nullptr, nullptr, nullptr);
  ln_kernel<<<8192, 256, 0, stream>>>(x_mid, g2, be2, h);
  gemm_kernel<2><<<dim3(128,8), 512, 0, stream>>>(h, w1T, 32768, 2048, 512,
      b1, nullptr, nullptr, ff, nullptr, nullptr, nullptr);
  gemm_kernel<3><<<dim3(128,2), 512, 0, stream>>>(ff, w2T, 32768, 512, 2048,
      b2, x_mid, (float*)d_out, nullptr, nullptr, nullptr, nullptr);
}

// Round 9
// 588.352 us; speedup vs baseline: 1.1174x; 1.0294x over previous
//
#include <hip/hip_runtime.h>
#include <hip/hip_bf16.h>

typedef unsigned short ushort_t;
typedef __attribute__((ext_vector_type(8))) short short8;
typedef __attribute__((ext_vector_type(8))) unsigned short ushort8;
typedef __attribute__((ext_vector_type(4))) float f32x4;
typedef __attribute__((ext_vector_type(4))) unsigned int u32x4;
typedef long long i64;

__device__ __forceinline__ ushort_t f2bf(float f) {
  union { float f; unsigned int u; } c; c.f = f;
  unsigned int u = c.u;
  return (ushort_t)((u + 0x7fffu + ((u >> 16) & 1u)) >> 16);
}
__device__ __forceinline__ float bfbits_lo(unsigned int u) {
  union { unsigned int u; float f; } c; c.u = u << 16; return c.f;
}
__device__ __forceinline__ float bfbits_hi(unsigned int u) {
  union { unsigned int u; float f; } c; c.u = u & 0xffff0000u; return c.f;
}

__device__ __forceinline__ void gload_lds16(const void* g, void* l) {
  __builtin_amdgcn_global_load_lds(
      (__attribute__((address_space(1))) void*)(void*)g,
      (__attribute__((address_space(3))) void*)l, 16, 0, 0);
}

__device__ __forceinline__ void bar_lds() {
  asm volatile("s_waitcnt lgkmcnt(0)" ::: "memory");
  __builtin_amdgcn_s_barrier();
  asm volatile("" ::: "memory");
}
__device__ __forceinline__ void bar_full() {
  asm volatile("s_waitcnt vmcnt(0) lgkmcnt(0)" ::: "memory");
  __builtin_amdgcn_s_barrier();
  asm volatile("" ::: "memory");
}

// swizzled LDS fragment read: row-major 128B rows, 16B granule XOR
#define LDSF(base, row, g) \
  (*(const short8*)((base) + (row)*128 + (((g) ^ ((row)&7)) << 4)))

// ---------------- LayerNorm: f32 in -> bf16 out, D=512, one row per wave ----
__global__ __launch_bounds__(256) void ln_kernel(
    const float* __restrict__ x, const float* __restrict__ g,
    const float* __restrict__ be, ushort_t* __restrict__ out)
{
  const int lane = threadIdx.x & 63, wid = threadIdx.x >> 6;
  const size_t row = (size_t)blockIdx.x * 4 + wid;
  const float* xr = x + row * 512 + lane * 8;
  float4 v0 = *(const float4*)xr;
  float4 v1 = *(const float4*)(xr + 4);
  float vv[8] = {v0.x,v0.y,v0.z,v0.w,v1.x,v1.y,v1.z,v1.w};
  float s = 0;
#pragma unroll
  for (int e = 0; e < 8; ++e) s += vv[e];
#pragma unroll
  for (int o = 1; o < 64; o <<= 1) s += __shfl_xor(s, o);
  float mu = s * (1.0f/512.0f);
  float sq = 0;
#pragma unroll
  for (int e = 0; e < 8; ++e) { float d = vv[e]-mu; sq += d*d; }
#pragma unroll
  for (int o = 1; o < 64; o <<= 1) sq += __shfl_xor(sq, o);
  float rinv = rsqrtf(sq * (1.0f/512.0f) + 1e-5f);
  const float* gp = g + lane*8; const float* bp = be + lane*8;
  float4 ga = *(const float4*)gp, gb = *(const float4*)(gp+4);
  float4 ba = *(const float4*)bp, bb4 = *(const float4*)(bp+4);
  float gg[8] = {ga.x,ga.y,ga.z,ga.w,gb.x,gb.y,gb.z,gb.w};
  float bb[8] = {ba.x,ba.y,ba.z,ba.w,bb4.x,bb4.y,bb4.z,bb4.w};
  ushort8 o8;
#pragma unroll
  for (int e = 0; e < 8; ++e) o8[e] = f2bf((vv[e]-mu)*rinv*gg[e] + bb[e]);
  *(ushort8*)(out + row*512 + lane*8) = o8;
}

// ---------------- Weight transpose (tiled, coalesced both sides) -----------
__global__ __launch_bounds__(256) void wt_kernel(
    const float* __restrict__ w, ushort_t* __restrict__ wT, int K, int N)
{
  __shared__ float t[64][65];
  const int k0 = blockIdx.x * 64, n0 = blockIdx.y * 64;
  const int c = threadIdx.x & 63, r4 = threadIdx.x >> 6;
#pragma unroll
  for (int rr = 0; rr < 64; rr += 4)
    t[rr + r4][c] = w[(size_t)(k0 + rr + r4) * N + n0 + c];
  __syncthreads();
#pragma unroll
  for (int rr = 0; rr < 64; rr += 4)
    wT[(size_t)(n0 + rr + r4) * K + k0 + c] = f2bf(t[c][rr + r4]);
}

// ---------------- Rel-table prep ------------------------------------------
// rqp/rkp: (r,d) bf16, 256 rows (zero-padded >=225); rqp pre-scaled 0.125
// rv8    : (d,r) fp8 e4m3, 64 x 256
// tbl    : u32[256]: lo16 = bf16(0.125*rq[r].rk[r]), b16-23 = dx, b24-31 = dy
__global__ __launch_bounds__(256) void prep_rel_kernel(
    const float* __restrict__ rq, const float* __restrict__ rk,
    const float* __restrict__ rv,
    ushort_t* __restrict__ rqp, ushort_t* __restrict__ rkp,
    unsigned char* __restrict__ rv8, unsigned int* __restrict__ tbl)
{
  int id = blockIdx.x * 256 + threadIdx.x;
  if (id < 256*64) {
    int r = id >> 6;
    rqp[id] = (r < 225) ? f2bf(rq[id] * 0.125f) : (ushort_t)0;
    rkp[id] = (r < 225) ? f2bf(rk[id]) : (ushort_t)0;
  }
  if (id < 64*256) {
    int d = id >> 8, r = id & 255;
    float vv = (r < 225) ? rv[r*64+d] : 0.0f;
    int pk = __builtin_amdgcn_cvt_pk_fp8_f32(vv, vv, 0, 0);
    rv8[id] = (unsigned char)(pk & 0xff);
  }
  if (id < 256) {
    float s = 0; unsigned dx = 255, dy = 255;
    if (id < 225) {
      for (int d2 = 0; d2 < 64; ++d2) s += rq[id*64+d2]*rk[id*64+d2];
      dx = id / 15; dy = id - dx*15;
    }
    tbl[id] = (unsigned)f2bf(s * 0.125f) | (dx << 16) | (dy << 24);
  }
}

// ---------------- bf16 GEMM: 256x256 tile, BK=64, 512 thr, 128KB LDS -------
// C = A(MxK) * Bt(NxK)^T.  Waves 2(M) x 4(N); per-wave 128x64 via acc[8][4].
// EPI 0: scatter qkv (XOR-swizzled head tiles)
// EPI 1/3: +bias +resid -> f32   EPI 2: relu+bias -> bf16
template<int EPI>
__global__ __launch_bounds__(512, 2) void gemm_kernel(
    const ushort_t* __restrict__ A, const ushort_t* __restrict__ Bt,
    int M, int N, int K,
    const float* __restrict__ bias, const float* __restrict__ resid,
    float* __restrict__ outf, ushort_t* __restrict__ outb,
    ushort_t* __restrict__ qb, ushort_t* __restrict__ kb,
    ushort_t* __restrict__ vtb)
{
  __shared__ __align__(16) ushort_t lds[65536];  // 2 x (A 32KB + B 32KB)
  const int tid = threadIdx.x, lane = tid & 63, wid = tid >> 6;
  const int m0 = blockIdx.x * 256, n0 = blockIdx.y * 256;
  const int l15 = lane & 15, lh = lane >> 4;
  const int wm = wid >> 2, wn = wid & 3;

  f32x4 acc[8][4] = {};
  const int NT = K >> 6;

  auto stage = [&](int buf, int kt) {
    const int k0 = kt << 6;
#pragma unroll
    for (int p = 0; p < 4; ++p) {
      const int lofs = p*8192 + tid*16;            // byte offset in 32KB half
      const int row = lofs >> 7;                   // 0..255
      const int sc = ((tid & 7) ^ (row & 7)) << 3; // swizzled src col (elems)
      gload_lds16(A  + (size_t)(m0 + row) * K + (k0 + sc),
                  &lds[buf*32768 + (lofs >> 1)]);
      gload_lds16(Bt + (size_t)(n0 + row) * K + (k0 + sc),
                  &lds[buf*32768 + 16384 + (lofs >> 1)]);
    }
  };

  stage(0, 0);
  __syncthreads();
  for (int t = 0; t < NT; ++t) {
    if (t + 1 < NT) stage((t+1) & 1, t+1);
    const ushort_t* Ab = &lds[(t&1)*32768];
    const ushort_t* Bb = Ab + 16384;
    short8 bfr[4][2];
#pragma unroll
    for (int ni = 0; ni < 4; ++ni) {
      const int row = wn*64 + ni*16 + l15;
#pragma unroll
      for (int kh = 0; kh < 2; ++kh)
        bfr[ni][kh] = *(const short8*)((const char*)Bb + row*128 +
                                       (((kh*4+lh) ^ (row&7))<<4));
    }
#pragma unroll
    for (int mi = 0; mi < 8; ++mi) {
      const int row = wm*128 + mi*16 + l15;
      short8 a0 = *(const short8*)((const char*)Ab + row*128 + ((lh     ^ (row&7))<<4));
      short8 a1 = *(const short8*)((const char*)Ab + row*128 + (((4+lh) ^ (row&7))<<4));
#pragma unroll
      for (int ni = 0; ni < 4; ++ni) {
        acc[mi][ni] = __builtin_amdgcn_mfma_f32_16x16x32_bf16(a0, bfr[ni][0], acc[mi][ni], 0,0,0);
        acc[mi][ni] = __builtin_amdgcn_mfma_f32_16x16x32_bf16(a1, bfr[ni][1], acc[mi][ni], 0,0,0);
      }
    }
    __syncthreads();
  }

#pragma unroll
  for (int mi = 0; mi < 8; ++mi)
#pragma unroll
    for (int ni = 0; ni < 4; ++ni)
#pragma unroll
      for (int r = 0; r < 4; ++r) {
        const int grow = m0 + wm*128 + mi*16 + lh*4 + r;
        const int gcol = n0 + wn*64 + ni*16 + l15;
        const float v = acc[mi][ni][r];
        if constexpr (EPI == 0) {
          const int sel = gcol >> 9, c5 = gcol & 511;
          const int hh = c5 >> 6, d = c5 & 63;
          const size_t bh = (size_t)((grow >> 6) * 8 + hh);
          const int i = grow & 63;
          if (sel == 0)
            qb[(bh<<12) + i*64 + (((d>>3)^(i&7))<<3) + (d&7)] = f2bf(v * 0.125f);
          else if (sel == 1)
            kb[(bh<<12) + i*64 + (((d>>3)^(i&7))<<3) + (d&7)] = f2bf(v);
          else
            vtb[(bh<<12) + d*64 + (((i>>3)^(d&7))<<3) + (i&7)] = f2bf(v);
        } else if constexpr (EPI == 2) {
          float t2 = v + bias[gcol];
          outb[(size_t)grow * N + gcol] = f2bf(t2 > 0.0f ? t2 : 0.0f);
        } else {
          const size_t o = (size_t)grow * N + gcol;
          outf[o] = v + bias[gcol] + resid[o];
        }
      }
}

// ---------------- Fused relative attention --------------------------------
// One head per 512-thread block (8 waves; wave = (ib, half)).
// q/k/vT staged to LDS via global_load_lds (pre-swizzled by GEMM EPI0);
// rkp/rqp/rv8 from L2 with explicit load batching (launch_bounds(512,2)
// gives 256-VGPR budget). LDS 58368B => 2 blocks/CU.
__global__ __launch_bounds__(512, 2) void attn_kernel(
    const ushort_t* __restrict__ qb, const ushort_t* __restrict__ kb,
    const ushort_t* __restrict__ vtb,
    const ushort_t* __restrict__ rkp, const ushort_t* __restrict__ rqp,
    const unsigned char* __restrict__ rv8, const unsigned int* __restrict__ tbl_g,
    ushort_t* __restrict__ attn_out)
{
  __shared__ __align__(16) char smem[58368];
  char* qS  = smem;                 //  8KB swizzled q  [64 rows]x128B
  char* kS  = smem + 8192;          //  8KB swizzled k
  char* vS  = smem + 16384;         //  8KB swizzled vT [64 d-rows]x128B
  char* qkB = smem + 24576;         // 16KB f32 logits overlay
  char* t23B = smem + 40960;        // 16KB u32 t2/t3 overlay
  unsigned int* tblS = (unsigned int*)(smem + 57344);
  char* attnSB = smem + 24576;      // alias post-softmax (8KB)
  char* S8B   = smem + 32768;       // alias post-softmax (16KB)

  const int tid = threadIdx.x, lane = tid & 63, wid = tid >> 6;
  const int ib = wid >> 1, half = wid & 1;
  const int l15 = lane & 15, lh = lane >> 4;
  const int rowA = ib*16 + l15;
  const int bh = blockIdx.x;

  // ---- bulk stage: 3 x 16B per thread + tbl ------------------------------
  gload_lds16((const char*)qb  + ((size_t)bh<<13) + tid*16, qS + tid*16);
  gload_lds16((const char*)kb  + ((size_t)bh<<13) + tid*16, kS + tid*16);
  gload_lds16((const char*)vtb + ((size_t)bh<<13) + tid*16, vS + tid*16);
  if (tid < 64)
    gload_lds16((const char*)tbl_g + tid*16, (char*)tblS + tid*16);
  bar_full();

  // per-r row constants
  const int ibase = ib*16 + lh*4;
  int xi7[4], yi7[4];
#pragma unroll
  for (int r = 0; r < 4; ++r) {
    const int i = ibase + r;
    xi7[r] = (i >> 3) + 7; yi7[r] = (i & 7) + 7;
  }

  // ---- P1a: QK^T (wave pair splits jb) ----------------------------------
  short8 qf0 = LDSF(qS, rowA, lh);
  short8 qf1 = LDSF(qS, rowA, 4+lh);
#pragma unroll
  for (int t = 0; t < 2; ++t) {
    const int jb = half*2 + t;
    const int rowK = jb*16 + l15;
    short8 b0 = LDSF(kS, rowK, lh);
    short8 b1 = LDSF(kS, rowK, 4+lh);
    f32x4 a = {};
    a = __builtin_amdgcn_mfma_f32_16x16x32_bf16(qf0, b0, a, 0,0,0);
    a = __builtin_amdgcn_mfma_f32_16x16x32_bf16(qf1, b1, a, 0,0,0);
#pragma unroll
    for (int r = 0; r < 4; ++r) {
      const int i = ibase + r;
      const int gcol = jb*16 + l15;
      *(float*)(qkB + i*256 + ((((gcol>>2) ^ (i&7)))<<4) + (gcol&3)*4) = a[r];
    }
  }

  // ---- P1b: t2 = q @ rel_k^T + C0, pure store into t23.lo ---------------
  // batched: 8 L2 loads in flight per 4-s chunk
#pragma unroll
  for (int sb = 0; sb < 2; ++sb) {
    short8 lb[8];
#pragma unroll
    for (int c = 0; c < 4; ++c) {
      const int rowr = (half*8 + sb*4 + c)*16 + l15;
      lb[c*2]   = *(const short8*)(rkp + rowr*64 + lh*8);
      lb[c*2+1] = *(const short8*)(rkp + rowr*64 + 32 + lh*8);
    }
    f32x4 a4[4] = {};
#pragma unroll
    for (int c = 0; c < 4; ++c) {
      a4[c] = __builtin_amdgcn_mfma_f32_16x16x32_bf16(qf0, lb[c*2],   a4[c], 0,0,0);
      a4[c] = __builtin_amdgcn_mfma_f32_16x16x32_bf16(qf1, lb[c*2+1], a4[c], 0,0,0);
    }
#pragma unroll
    for (int c = 0; c < 4; ++c) {
      const int rowr = (half*8 + sb*4 + c)*16 + l15;
      const unsigned tb = tblS[rowr];
      const float c0v = bfbits_lo(tb);
      const int dx = (tb >> 16) & 0xff, dy = tb >> 24;
#pragma unroll
      for (int r = 0; r < 4; ++r) {
        const int xj = xi7[r] - dx, yj = yi7[r] - dy;
        if (((xj | yj) & ~7) == 0) {
          const int i = ibase + r;
          const int j = xj*8 + yj;
          *(ushort_t*)(t23B + i*256 + (((j>>2) ^ (i&7))<<4) + (j&3)*4)
              = f2bf(a4[c][r] + c0v);
        }
      }
    }
  }

  // ---- P1c: t3 = k @ rel_q^T (pre-scaled), pure store into t23.hi -------
  {
    short8 kf0 = LDSF(kS, rowA, lh);
    short8 kf1 = LDSF(kS, rowA, 4+lh);
#pragma unroll
    for (int sb = 0; sb < 2; ++sb) {
      short8 lb[8];
#pragma unroll
      for (int c = 0; c < 4; ++c) {
        const int rowr = (half*8 + sb*4 + c)*16 + l15;
        lb[c*2]   = *(const short8*)(rqp + rowr*64 + lh*8);
        lb[c*2+1] = *(const short8*)(rqp + rowr*64 + 32 + lh*8);
      }
      f32x4 a4[4] = {};
#pragma unroll
      for (int c = 0; c < 4; ++c) {
        a4[c] = __builtin_amdgcn_mfma_f32_16x16x32_bf16(kf0, lb[c*2],   a4[c], 0,0,0);
        a4[c] = __builtin_amdgcn_mfma_f32_16x16x32_bf16(kf1, lb[c*2+1], a4[c], 0,0,0);
      }
#pragma unroll
      for (int c = 0; c < 4; ++c) {
        const int rowr = (half*8 + sb*4 + c)*16 + l15;
        const unsigned tb = tblS[rowr];
        const int dx = (tb >> 16) & 0xff, dy = tb >> 24;
#pragma unroll
        for (int r = 0; r < 4; ++r) {
          const int xi = xi7[r] + dx - 14, yi = yi7[r] + dy - 14;
          if (((xi | yi) & ~7) == 0) {
            const int i2 = xi*8 + yi;
            const int j = ibase + r;
            *(ushort_t*)(t23B + i2*256 + (((j>>2) ^ (i2&7))<<4) + (j&3)*4 + 2)
                = f2bf(a4[c][r]);
          }
        }
      }
    }
  }
  bar_lds();  // BAR1: logits + t23 complete

  // ---- P2: softmax (pure vector reads) -----------------------------------
  const int i = tid >> 3, qq = tid & 7;
  float av[8];
  {
    float mx = -1e30f;
#pragma unroll
    for (int h = 0; h < 2; ++h) {
      const int g = 2*qq + h;
      const int off = i*256 + ((g ^ (i&7))<<4);
      f32x4 lf = *(const f32x4*)(qkB + off);
      u32x4 u  = *(const u32x4*)(t23B + off);
#pragma unroll
      for (int e = 0; e < 4; ++e) {
        float v = lf[e] + bfbits_lo(u[e]) + bfbits_hi(u[e]);
        av[h*4+e] = v; mx = fmaxf(mx, v);
      }
    }
    mx = fmaxf(mx, __shfl_xor(mx, 1));
    mx = fmaxf(mx, __shfl_xor(mx, 2));
    mx = fmaxf(mx, __shfl_xor(mx, 4));
    float s = 0;
#pragma unroll
    for (int e = 0; e < 8; ++e) { float ev = __expf(av[e]-mx); av[e] = ev; s += ev; }
    s += __shfl_xor(s, 1); s += __shfl_xor(s, 2); s += __shfl_xor(s, 4);
    const float inv = 1.0f / s;
#pragma unroll
    for (int e = 0; e < 8; ++e) av[e] *= inv;
  }
  bar_lds();  // BAR2: all logits/t23 reads done; overlay may be rewritten

  // ---- P3: write attnS (bf16) + S8 (fp8 scatter) -------------------------
  {
    ushort8 w;
#pragma unroll
    for (int e = 0; e < 8; ++e) w[e] = f2bf(av[e]);
    *(ushort8*)(attnSB + i*128 + ((qq ^ (i&7))<<4)) = w;
#pragma unroll
    for (int u8 = 0; u8 < 4; ++u8)
      *(i64*)(S8B + i*256 + (((qq*4 + u8) ^ (i&7))<<3)) = 0;
    const int xi8 = i >> 3, yi8 = i & 7;
#pragma unroll
    for (int jj = 0; jj < 8; jj += 2) {
      const int j0 = qq*8 + jj;
      int pk = __builtin_amdgcn_cvt_pk_fp8_f32(av[jj], av[jj+1], 0, 0);
      const int rr0 = (xi8 - (j0>>3) + 7)*15 + (yi8 - (j0&7) + 7);
      const int rr1 = (xi8 - ((j0+1)>>3) + 7)*15 + (yi8 - ((j0+1)&7) + 7);
      *(unsigned char*)(S8B + i*256 + (((rr0>>3) ^ (i&7))<<3) + (rr0&7))
          = (unsigned char)(pk & 0xff);
      *(unsigned char*)(S8B + i*256 + (((rr1>>3) ^ (i&7))<<3) + (rr1&7))
          = (unsigned char)((pk >> 8) & 0xff);
    }
  }
  bar_lds();  // BAR3: attnS/S8 complete

  // ---- P4: out = attn @ v (bf16) + S @ rel_v^T (fp8), 2 tiles per wave ---
#pragma unroll
  for (int t = 0; t < 2; ++t) {
    const int db = half*2 + t;
    const int rowV = db*16 + l15;
    i64 b8v[8];
#pragma unroll
    for (int ks = 0; ks < 8; ++ks)
      b8v[ks] = *(const i64*)(rv8 + (size_t)rowV*256 + ks*32 + lh*8);
    f32x4 a = {};
#pragma unroll
    for (int ks = 0; ks < 8; ++ks) {
      i64 a8 = *(const i64*)(S8B + rowA*256 + (((ks*4+lh) ^ (rowA&7))<<3));
      a = __builtin_amdgcn_mfma_f32_16x16x32_fp8_fp8(a8, b8v[ks], a, 0,0,0);
    }
    {
      short8 bv0 = LDSF(vS, rowV, lh);
      short8 bv1 = LDSF(vS, rowV, 4+lh);
      short8 aa0 = *(const short8*)(attnSB + rowA*128 + ((lh ^ (rowA&7))<<4));
      short8 aa1 = *(const short8*)(attnSB + rowA*128 + (((4+lh) ^ (rowA&7))<<4));
      a = __builtin_amdgcn_mfma_f32_16x16x32_bf16(aa0, bv0, a, 0,0,0);
      a = __builtin_amdgcn_mfma_f32_16x16x32_bf16(aa1, bv1, a, 0,0,0);
    }
    const int b_idx = bh >> 3, hh = bh & 7;
#pragma unroll
    for (int r = 0; r < 4; ++r)
      attn_out[((size_t)(b_idx*64 + ib*16 + lh*4 + r))*512 + hh*64 + db*16 + l15]
          = f2bf(a[r]);
  }
}

// ---------------------------------------------------------------------------
extern "C" void kernel_launch(void* const* d_in, const int* in_sizes, int n_in,
                              void* d_out, int out_size, void* d_ws, size_t ws_size,
                              hipStream_t stream)
{
  (void)in_sizes; (void)n_in; (void)out_size; (void)ws_size;
  const float* x     = (const float*)d_in[0];
  const float* w_qkv = (const float*)d_in[1];
  const float* w_proj= (const float*)d_in[2];
  const float* b_proj= (const float*)d_in[3];
  const float* w1    = (const float*)d_in[4];
  const float* b1    = (const float*)d_in[5];
  const float* w2    = (const float*)d_in[6];
  const float* b2    = (const float*)d_in[7];
  const float* g1    = (const float*)d_in[8];
  const float* be1   = (const float*)d_in[9];
  const float* g2    = (const float*)d_in[10];
  const float* be2   = (const float*)d_in[11];
  const float* rel_q = (const float*)d_in[12];
  const float* rel_k = (const float*)d_in[13];
  const float* rel_v = (const float*)d_in[14];

  char* ws = (char*)d_ws;
  const size_t MB = 1ull << 20;
  ushort_t* h      = (ushort_t*)(ws);            // 32MiB (reused as h2)
  ushort_t* qb     = (ushort_t*)(ws + 32*MB);
  ushort_t* kb     = (ushort_t*)(ws + 64*MB);
  ushort_t* vtb    = (ushort_t*)(ws + 96*MB);
  ushort_t* attn_o = (ushort_t*)(ws + 128*MB);
  ushort_t* ff     = (ushort_t*)(ws + 32*MB);    // aliases qb..attn_o (dead)
  float*    x_mid  = (float*)(ws + 160*MB);      // 64MiB
  char* wreg = ws + 224*MB;
  ushort_t* wqkvT = (ushort_t*)(wreg);
  ushort_t* wprojT= (ushort_t*)(wreg + 1572864);
  ushort_t* w1T   = (ushort_t*)(wreg + 2097152);
  ushort_t* w2T   = (ushort_t*)(wreg + 4194304);
  ushort_t*      rkp  = (ushort_t*)(wreg + 6291456);   // 256x64 bf16
  ushort_t*      rqp  = (ushort_t*)(wreg + 6324224);   // 256x64 bf16
  unsigned char* rv8  = (unsigned char*)(wreg + 6356992); // 64x256 fp8
  unsigned int*  tbl  = (unsigned int*)(wreg + 6373376);  // u32[256]

  wt_kernel<<<dim3(8,24), 256, 0, stream>>>(w_qkv, wqkvT, 512, 1536);
  wt_kernel<<<dim3(8,8),  256, 0, stream>>>(w_proj, wprojT, 512, 512);
  wt_kernel<<<dim3(8,32), 256, 0, stream>>>(w1, w1T, 512, 2048);
  wt_kernel<<<dim3(32,8), 256, 0, stream>>>(w2, w2T, 2048, 512);
  prep_rel_kernel<<<64, 256, 0, stream>>>(rel_q, rel_k, rel_v,
      rqp, rkp, rv8, tbl);

  ln_kernel<<<8192, 256, 0, stream>>>(x, g1, be1, h);
  gemm_kernel<0><<<dim3(128,6), 512, 0, stream>>>(h, wqkvT, 32768, 1536, 512,
      nullptr, nullptr, nullptr, nullptr, qb, kb, vtb);
  attn_kernel<<<4096, 512, 0, stream>>>(qb, kb, vtb,
      rkp, rqp, rv8, tbl, attn_o);
  gemm_kernel<1><<<dim3(128,2), 512, 0, stream>>>(attn_o, wprojT, 32768, 512, 512,
      b_proj, x, x_mid, nullptr, nullptr, nullptr, nullptr);
  ln_kernel<<<8192, 256, 0, stream>>>(x_mid, g2, be2, h);
  gemm_kernel<2><<<dim3(128,8), 512, 0, stream>>>(h, w1T, 32768, 2048, 512,
      b1, nullptr, nullptr, ff, nullptr, nullptr, nullptr);
  gemm_kernel<3><<<dim3(128,2), 512, 0, stream>>>(ff, w2T, 32768, 512, 2048,
      b2, x_mid, (float*)d_out, nullptr, nullptr, nullptr, nullptr);
}